// Round 14
// baseline (14.922 us; speedup 1.0000x reference)
//
#include <hip/hip_runtime.h>
#include <math.h>

// SpheresRasterizer: B=1, N=1024, H=W=256, K=8.
// Round 14: per-WAVE 8x8 quadrant scan.
//  Phase A (256 threads): transform all N points -> LDS stage (R13-exact).
//  Phase B (per wave, independent): cull staged points to the wave's 8x8
//    quadrant box, ballot-compact (ascending index) into a private LDS list.
//  Phase C (per wave): R13 packed-u64-key top-8 scan of the private list.
//  Worst dense tile's 4 quadrants run concurrently on the CU's 4 SIMDs.

#define KPP 8
#define BW  8
#define TS  16
#define CAP 256          // per-wave list capacity (worst quadrant ~60 here)

typedef float vf4 __attribute__((ext_vector_type(4)));

static __device__ __forceinline__ void nt_store4(float* p, float a, float b, float c, float d) {
    vf4 v = {a, b, c, d};
    __builtin_nontemporal_store(v, (vf4*)p);
}

__global__ __launch_bounds__(256) void sphere_raster_kernel(
    const float* __restrict__ points,   // B*N*3
    const float* __restrict__ radius,   // B*N
    const float* __restrict__ w2v,      // B*16
    const float* __restrict__ proj,     // B*16
    float* __restrict__ out,            // 3 * B*H*W*KPP floats
    int B, int N, int H, int W)
{
    extern __shared__ char smem[];
    float4* sh = (float4*)smem;                                   // N staged
    // per-wave regions (CAP+16 slack for sentinel pad)
    float4* cmpw  = (float4*)(smem + (size_t)N * 16);             // 4*(CAP+16)
    int*    cidxw = (int*)(smem + (size_t)N * 16 + 4 * (CAP + 16) * 16);

    const int tid      = threadIdx.x;
    const int lane     = tid & 63;
    const int wid      = tid >> 6;
    const int tilesX   = W / TS;
    const int tilesPer = tilesX * (H / TS);
    const int tile     = blockIdx.x % tilesPer;
    const int b        = blockIdx.x / tilesPer;
    const int tx0      = (tile % tilesX) * TS;
    const int ty0      = (tile / tilesX) * TS;
    // wave quadrant origin
    const int qx = tx0 + (wid & 1) * 8;
    const int qy = ty0 + (wid >> 1) * 8;
    // this lane's pixel within the quadrant
    const int j = qx + (lane & 7);
    const int i = qy + (lane >> 3);

    const float* M1 = w2v  + (size_t)b * 16;
    const float* M2 = proj + (size_t)b * 16;

    const double halfd = 1.0 - 1.0 / (double)W;
    const double stepd = 2.0 * halfd / (double)(W - 1);
    const float px = (float)(halfd - (double)j * stepd);
    const float py = (float)(halfd - (double)i * stepd);
    // 8x8 quadrant box (center +/- hext), +1px inflation
    const float cxw = (float)(halfd - ((double)qx + 3.5) * stepd);
    const float cyw = (float)(halfd - ((double)qy + 3.5) * stepd);
    const float hext = (float)(4.5 * stepd);

    // ---- Phase A: transform 4 contiguous points/thread -> sh (R13-exact) ----
    {
        const int t0 = tid * 4;
        const float4* pv = (const float4*)(points + ((size_t)b * N + t0) * 3);
        float4 q0 = pv[0], q1 = pv[1], q2 = pv[2];
        float4 rr = *(const float4*)(radius + (size_t)b * N + t0);
        float xs[4] = {q0.x, q0.w, q1.z, q2.y};
        float ys[4] = {q0.y, q1.x, q1.w, q2.z};
        float zs[4] = {q0.z, q1.y, q2.x, q2.w};
        float rv[4] = {rr.x, rr.y, rr.z, rr.w};
#pragma unroll
        for (int s = 0; s < 4; ++s) {
            float x = xs[s], y = ys[s], z = zs[s];
            float vx = ((x * M1[0] + y * M1[4]) + z * M1[8])  + M1[12];
            float vy = ((x * M1[1] + y * M1[5]) + z * M1[9])  + M1[13];
            float vz = ((x * M1[2] + y * M1[6]) + z * M1[10]) + M1[14];
            float vw = ((x * M1[3] + y * M1[7]) + z * M1[11]) + M1[15];
            float w1 = (fabsf(vw) < 1e-8f) ? 1e-8f : vw;
            vx /= w1; vy /= w1; vz /= w1;
            float sx = ((vx * M2[0] + vy * M2[4]) + vz * M2[8])  + M2[12];
            float sy = ((vx * M2[1] + vy * M2[5]) + vz * M2[9])  + M2[13];
            float sw = ((vx * M2[3] + vy * M2[7]) + vz * M2[11]) + M2[15];
            float w2 = (fabsf(sw) < 1e-8f) ? 1e-8f : sw;
            sx /= w2; sy /= w2;
            float r = rv[s];
            float r2eff = (vz > 0.0f) ? r * r : -1.0f;
            sh[t0 + s] = make_float4(sx, sy, vz, r2eff);
        }
    }
    __syncthreads();

    // ---- Phase B: per-wave cull + ballot compaction (ascending index) ----
    float4* cmp  = cmpw  + wid * (CAP + 16);
    int*    cidx = cidxw + wid * (CAP + 16);
    int M = 0;
    const unsigned long long ltmask = (lane == 0) ? 0ULL : (~0ULL >> (64 - lane));
#pragma unroll 1
    for (int s = 0; s < 16; ++s) {
        int idx = s * 64 + lane;
        float4 p = sh[idx];
        float dxm = fmaxf(0.0f, fabsf(p.x - cxw) - hext);
        float dym = fmaxf(0.0f, fabsf(p.y - cyw) - hext);
        float dmin2 = dxm * dxm + dym * dym;
        int keep = (dmin2 <= p.w + 1e-6f) ? 1 : 0;
        unsigned long long mask = __ballot(keep);
        int pos = M + __popcll(mask & ltmask);
        if (keep && pos < CAP) { cmp[pos] = p; cidx[pos] = idx; }
        M += __popcll(mask);
    }
    if (M > CAP) M = CAP;
    const int Mpad = (M + 2 * BW - 1) & ~(2 * BW - 1);
    if (lane < Mpad - M) {
        cmp[M + lane]  = make_float4(0.0f, 0.0f, 0.0f, -1.0f);  // never inside
        cidx[M + lane] = -1;
    }
    // wave-private region; ds ops within a wave are ordered — no barrier needed

    // ---- Phase C: double-buffered 8-wide scan, packed-u64 top-K (R13) ----
    unsigned long long kb[KPP];
#pragma unroll
    for (int k = 0; k < KPP; ++k) kb[k] = ~0ULL;

    auto process = [&](const float4* pp, int base) {
#pragma unroll
        for (int u = 0; u < BW; ++u) {
            float dx = pp[u].x - px;
            float dy = pp[u].y - py;
            float dist2 = __fadd_rn(__fmul_rn(dx, dx), __fadd_rn(__fmul_rn(dy, dy), 0.0f));
            dist2 = __fadd_rn(__fmul_rn(dx, dx), __fmul_rn(dy, dy));
            unsigned long long key =
                ((unsigned long long)__float_as_uint(pp[u].z) << 32) |
                (unsigned)(base + u);
            if ((dist2 <= pp[u].w) && (key < kb[KPP - 1])) {
                unsigned long long kc = key;
#pragma unroll
                for (int k2 = 0; k2 < KPP; ++k2) {
                    unsigned long long t = kb[k2];
                    bool lt = (kc < t);
                    kb[k2] = lt ? kc : t;
                    kc     = lt ? t  : kc;
                }
            }
        }
    };

    float4 pa[BW];
    float4 pb[BW];
#pragma unroll
    for (int u = 0; u < BW; ++u) pa[u] = cmp[u];

    for (int n = 0; n < Mpad; n += 2 * BW) {
#pragma unroll
        for (int u = 0; u < BW; ++u) pb[u] = cmp[n + BW + u];
        process(pa, n);
        if (n + 2 * BW < Mpad) {
#pragma unroll
            for (int u = 0; u < BW; ++u) pa[u] = cmp[n + 2 * BW + u];
        }
        process(pb, n + BW);
    }

    // ---- Phase D: unpack, recompute dist2 bit-identically, nt-store ----
    const size_t pix   = ((size_t)b * H + i) * W + j;
    const size_t plane = (size_t)B * H * W * KPP;
    float vidx[KPP], vzbf[KPP], vdst[KPP];
#pragma unroll
    for (int k = 0; k < KPP; ++k) {
        unsigned long long key = kb[k];
        bool valid = (key != ~0ULL);
        int p2 = valid ? (int)(key & 0xFFFFFFFFu) : 0;
        float4 p = cmp[p2];
        int idx  = cidx[p2];
        float dx = p.x - px;
        float dy = p.y - py;
        float dist2 = __fadd_rn(__fmul_rn(dx, dx), __fmul_rn(dy, dy));
        float z = __uint_as_float((unsigned)(key >> 32));
        vidx[k] = valid ? (float)idx : -1.0f;
        vzbf[k] = valid ? z          : -1.0f;
        vdst[k] = valid ? dist2      : -1.0f;
    }
    float* oidx = out + pix * KPP;
    float* ozbf = out + plane + pix * KPP;
    float* odst = out + 2 * plane + pix * KPP;
    nt_store4(oidx,     vidx[0], vidx[1], vidx[2], vidx[3]);
    nt_store4(oidx + 4, vidx[4], vidx[5], vidx[6], vidx[7]);
    nt_store4(ozbf,     vzbf[0], vzbf[1], vzbf[2], vzbf[3]);
    nt_store4(ozbf + 4, vzbf[4], vzbf[5], vzbf[6], vzbf[7]);
    nt_store4(odst,     vdst[0], vdst[1], vdst[2], vdst[3]);
    nt_store4(odst + 4, vdst[4], vdst[5], vdst[6], vdst[7]);
}

extern "C" void kernel_launch(void* const* d_in, const int* in_sizes, int n_in,
                              void* d_out, int out_size, void* d_ws, size_t ws_size,
                              hipStream_t stream) {
    const float* points = (const float*)d_in[0];
    const float* radius = (const float*)d_in[1];
    const float* w2v    = (const float*)d_in[2];
    const float* proj   = (const float*)d_in[3];
    int B = in_sizes[2] / 16;
    if (B < 1) B = 1;
    int N = in_sizes[1] / B;
    int HW = out_size / (3 * B * KPP);
    int H = 1;
    while ((H + 1) * (H + 1) <= HW) ++H;     // integer sqrt
    int W = H;

    int tiles = (W / TS) * (H / TS);
    // LDS: sh N*16 + 4 wave-lists of (CAP+16)*(16+4)
    size_t shmem = (size_t)N * 16 + (size_t)4 * (CAP + 16) * 20;
    sphere_raster_kernel<<<B * tiles, 256, shmem, stream>>>(
        points, radius, w2v, proj, (float*)d_out, B, N, H, W);
}

// Round 15
// 14.154 us; speedup vs baseline: 1.0543x; 1.0543x over previous
//
#include <hip/hip_runtime.h>
#include <math.h>

// SpheresRasterizer: B=1, N=1024, H=W=256, K=8.
// Round 15: block-parallel QUADRANT-LIST build + per-wave scan.
//  Phase 1 (256 thr, one pass): transform 4 pts/thread (R13-exact numerics);
//    test each point against the four 8x8 quadrant boxes (+1px inflation);
//    single u64-packed (4x16-bit) shfl prefix scan compacts all 4 lists at
//    once, order-preserving (ascending point index per list).
//  Phase 2: wave w scans ONLY quadrant-w's list (~0.5x the tile list) with
//    the R13 packed-u64-key top-8 chain. 4 dense quadrants run on 4 SIMDs.
//  Phase 3: unpack keys, recompute dist2 bit-identically, nt-store.

#define KPP 8
#define BW  8
#define TS  16
#define CAP 320          // per-quadrant list capacity (worst observed ~70)

typedef float vf4 __attribute__((ext_vector_type(4)));

static __device__ __forceinline__ void nt_store4(float* p, float a, float b, float c, float d) {
    vf4 v = {a, b, c, d};
    __builtin_nontemporal_store(v, (vf4*)p);
}

__global__ __launch_bounds__(256) void sphere_raster_kernel(
    const float* __restrict__ points,   // B*N*3
    const float* __restrict__ radius,   // B*N
    const float* __restrict__ w2v,      // B*16
    const float* __restrict__ proj,     // B*16
    float* __restrict__ out,            // 3 * B*H*W*KPP floats
    int B, int N, int H, int W)
{
    __shared__ float4 cmpL[4][CAP + 16];
    __shared__ int    cidxL[4][CAP + 16];
    __shared__ unsigned long long wsum64[4];

    const int tid      = threadIdx.x;
    const int lane     = tid & 63;
    const int wid      = tid >> 6;
    const int tilesX   = W / TS;
    const int tilesPer = tilesX * (H / TS);
    const int tile     = blockIdx.x % tilesPer;
    const int b        = blockIdx.x / tilesPer;
    const int tx0      = (tile % tilesX) * TS;
    const int ty0      = (tile / tilesX) * TS;
    // wave wid owns quadrant wid: (col, row) = (wid&1, wid>>1)
    const int qx = tx0 + (wid & 1) * 8;
    const int qy = ty0 + (wid >> 1) * 8;
    const int j  = qx + (lane & 7);
    const int i  = qy + (lane >> 3);

    const float* M1 = w2v  + (size_t)b * 16;
    const float* M2 = proj + (size_t)b * 16;

    const double halfd = 1.0 - 1.0 / (double)W;
    const double stepd = 2.0 * halfd / (double)(W - 1);
    const float px = (float)(halfd - (double)j * stepd);
    const float py = (float)(halfd - (double)i * stepd);
    // quadrant box centers (all 4, needed for classification) and half-extent
    float cqx[4], cqy[4];
#pragma unroll
    for (int q = 0; q < 4; ++q) {
        cqx[q] = (float)(halfd - ((double)(tx0 + (q & 1) * 8) + 3.5) * stepd);
        cqy[q] = (float)(halfd - ((double)(ty0 + (q >> 1) * 8) + 3.5) * stepd);
    }
    const float hext = (float)(4.5 * stepd);   // (8-1)/2 + 1 px inflation

    // ---- Phase 1: transform 4 pts/thread + 4-way quadrant classify ----
    const int t0 = tid * 4;
    float4 P[4];
    int km = 0;                               // keep bits: q*4+s
    unsigned long long pack = 0;              // 4x16-bit per-quadrant counts

    const float4* pv = (const float4*)(points + ((size_t)b * N + t0) * 3);
    float4 q0 = pv[0], q1 = pv[1], q2 = pv[2];
    float4 rr = *(const float4*)(radius + (size_t)b * N + t0);
    float xs[4] = {q0.x, q0.w, q1.z, q2.y};
    float ys[4] = {q0.y, q1.x, q1.w, q2.z};
    float zs[4] = {q0.z, q1.y, q2.x, q2.w};
    float rv[4] = {rr.x, rr.y, rr.z, rr.w};

#pragma unroll
    for (int s = 0; s < 4; ++s) {
        float x = xs[s], y = ys[s], z = zs[s];
        float vx = ((x * M1[0] + y * M1[4]) + z * M1[8])  + M1[12];
        float vy = ((x * M1[1] + y * M1[5]) + z * M1[9])  + M1[13];
        float vz = ((x * M1[2] + y * M1[6]) + z * M1[10]) + M1[14];
        float vw = ((x * M1[3] + y * M1[7]) + z * M1[11]) + M1[15];
        float w1 = (fabsf(vw) < 1e-8f) ? 1e-8f : vw;
        vx /= w1; vy /= w1; vz /= w1;
        float sx = ((vx * M2[0] + vy * M2[4]) + vz * M2[8])  + M2[12];
        float sy = ((vx * M2[1] + vy * M2[5]) + vz * M2[9])  + M2[13];
        float sw = ((vx * M2[3] + vy * M2[7]) + vz * M2[11]) + M2[15];
        float w2 = (fabsf(sw) < 1e-8f) ? 1e-8f : sw;
        sx /= w2; sy /= w2;
        float r = rv[s];
        float r2eff = (vz > 0.0f) ? r * r : -1.0f;
        P[s] = make_float4(sx, sy, vz, r2eff);
        float thr = r2eff + 1e-6f;
#pragma unroll
        for (int q = 0; q < 4; ++q) {
            float dxm = fmaxf(0.0f, fabsf(sx - cqx[q]) - hext);
            float dym = fmaxf(0.0f, fabsf(sy - cqy[q]) - hext);
            int keep = ((dxm * dxm + dym * dym) <= thr) ? 1 : 0;
            km  |= keep << (q * 4 + s);
            pack += keep ? (1ULL << (16 * q)) : 0ULL;
        }
    }

    // ---- single u64 prefix scan compacts all 4 lists at once ----
    unsigned long long pre = pack;
#pragma unroll
    for (int d = 1; d < 64; d <<= 1) {
        unsigned long long v = __shfl_up(pre, d);
        if (lane >= d) pre += v;
    }
    if (lane == 63) wsum64[wid] = pre;
    __syncthreads();
    unsigned long long exc = pre - pack;       // exclusive within wave
    unsigned long long prevW = 0, tot = 0;
#pragma unroll
    for (int w = 0; w < 4; ++w) {
        unsigned long long ws = wsum64[w];
        if (w < wid) prevW += ws;
        tot += ws;
    }

#pragma unroll
    for (int q = 0; q < 4; ++q) {
        int pos = (int)((prevW >> (16 * q)) & 0xFFFF) + (int)((exc >> (16 * q)) & 0xFFFF);
#pragma unroll
        for (int s = 0; s < 4; ++s) {
            if (km & (1 << (q * 4 + s))) {
                if (pos < CAP) { cmpL[q][pos] = P[s]; cidxL[q][pos] = t0 + s; }
                ++pos;
            }
        }
    }

    // wave wid pads its own list to a multiple of 16
    int Mw = (int)((tot >> (16 * wid)) & 0xFFFF);
    if (Mw > CAP) Mw = CAP;
    const int Mpad = (Mw + 2 * BW - 1) & ~(2 * BW - 1);
    if (lane < Mpad - Mw) {
        cmpL[wid][Mw + lane]  = make_float4(0.0f, 0.0f, 0.0f, -1.0f); // never inside
        cidxL[wid][Mw + lane] = -1;
    }
    __syncthreads();

    // ---- Phase 2: wave scans its quadrant list (R13 packed-key chain) ----
    const float4* cmp  = cmpL[wid];
    const int*    cidx = cidxL[wid];

    unsigned long long kb[KPP];
#pragma unroll
    for (int k = 0; k < KPP; ++k) kb[k] = ~0ULL;

    auto process = [&](const float4* pp, int base) {
#pragma unroll
        for (int u = 0; u < BW; ++u) {
            float dx = pp[u].x - px;
            float dy = pp[u].y - py;
            float dist2 = __fadd_rn(__fmul_rn(dx, dx), __fmul_rn(dy, dy));
            unsigned long long key =
                ((unsigned long long)__float_as_uint(pp[u].z) << 32) |
                (unsigned)(base + u);
            if ((dist2 <= pp[u].w) && (key < kb[KPP - 1])) {
                unsigned long long kc = key;
#pragma unroll
                for (int k2 = 0; k2 < KPP; ++k2) {
                    unsigned long long t = kb[k2];
                    bool lt = (kc < t);
                    kb[k2] = lt ? kc : t;
                    kc     = lt ? t  : kc;
                }
            }
        }
    };

    float4 pa[BW];
    float4 pb[BW];
#pragma unroll
    for (int u = 0; u < BW; ++u) pa[u] = cmp[u];

    for (int n = 0; n < Mpad; n += 2 * BW) {
#pragma unroll
        for (int u = 0; u < BW; ++u) pb[u] = cmp[n + BW + u];
        process(pa, n);
        if (n + 2 * BW < Mpad) {
#pragma unroll
            for (int u = 0; u < BW; ++u) pa[u] = cmp[n + 2 * BW + u];
        }
        process(pb, n + BW);
    }

    // ---- Phase 3: unpack, recompute dist2 bit-identically, nt-store ----
    const size_t pix   = ((size_t)b * H + i) * W + j;
    const size_t plane = (size_t)B * H * W * KPP;
    float vidx[KPP], vzbf[KPP], vdst[KPP];
#pragma unroll
    for (int k = 0; k < KPP; ++k) {
        unsigned long long key = kb[k];
        bool valid = (key != ~0ULL);
        int p2 = valid ? (int)(key & 0xFFFFFFFFu) : 0;
        float4 p = cmp[p2];
        int idx  = cidx[p2];
        float dx = p.x - px;
        float dy = p.y - py;
        float dist2 = __fadd_rn(__fmul_rn(dx, dx), __fmul_rn(dy, dy));
        float z = __uint_as_float((unsigned)(key >> 32));
        vidx[k] = valid ? (float)idx : -1.0f;
        vzbf[k] = valid ? z          : -1.0f;
        vdst[k] = valid ? dist2      : -1.0f;
    }
    float* oidx = out + pix * KPP;
    float* ozbf = out + plane + pix * KPP;
    float* odst = out + 2 * plane + pix * KPP;
    nt_store4(oidx,     vidx[0], vidx[1], vidx[2], vidx[3]);
    nt_store4(oidx + 4, vidx[4], vidx[5], vidx[6], vidx[7]);
    nt_store4(ozbf,     vzbf[0], vzbf[1], vzbf[2], vzbf[3]);
    nt_store4(ozbf + 4, vzbf[4], vzbf[5], vzbf[6], vzbf[7]);
    nt_store4(odst,     vdst[0], vdst[1], vdst[2], vdst[3]);
    nt_store4(odst + 4, vdst[4], vdst[5], vdst[6], vdst[7]);
}

extern "C" void kernel_launch(void* const* d_in, const int* in_sizes, int n_in,
                              void* d_out, int out_size, void* d_ws, size_t ws_size,
                              hipStream_t stream) {
    const float* points = (const float*)d_in[0];
    const float* radius = (const float*)d_in[1];
    const float* w2v    = (const float*)d_in[2];
    const float* proj   = (const float*)d_in[3];
    int B = in_sizes[2] / 16;
    if (B < 1) B = 1;
    int N = in_sizes[1] / B;
    int HW = out_size / (3 * B * KPP);
    int H = 1;
    while ((H + 1) * (H + 1) <= HW) ++H;     // integer sqrt
    int W = H;

    int tiles = (W / TS) * (H / TS);
    sphere_raster_kernel<<<B * tiles, 256, 0, stream>>>(
        points, radius, w2v, proj, (float*)d_out, B, N, H, W);
}

// Round 16
// 13.551 us; speedup vs baseline: 1.1011x; 1.0445x over previous
//
#include <hip/hip_runtime.h>
#include <math.h>

// SpheresRasterizer: B=1, N=1024, H=W=256, K=8.
// Round 16: REVERT to round-13 kernel — the measured best (13.62 us).
// R5/R12 skeleton; phase-2 top-K kept as a SINGLE packed u64 key
//   key = (float_bits(z) << 32) | list_pos
// (z>0 finite for all kept candidates -> IEEE bits order-isomorphic to z;
//  list_pos monotone in original index -> tie-break identical to reference).
// idx/dist2 stay out of the hot loop; dist2 recomputed bit-identically in
// the epilogue; z unpacked from the key; nt output stores.
//
// Session ledger (why this is the ceiling):
//   wall = launch(~2.1us, R7 probe) + harness-cold(~6-8us, invariant across
//   code size/scan structure/store policy/partitioning — R4..R15) + warm
//   (~5.3us, worst-center-tile top-K scan; R6/R11 amplified probes).
//   Tile 16x16 is optimal given max sphere radius ~10px (R15 null).

#define KPP 8
#define BW  8
#define TS  16

typedef float vf4 __attribute__((ext_vector_type(4)));

static __device__ __forceinline__ void nt_store4(float* p, float a, float b, float c, float d) {
    vf4 v = {a, b, c, d};
    __builtin_nontemporal_store(v, (vf4*)p);
}

__global__ __launch_bounds__(256) void sphere_raster_kernel(
    const float* __restrict__ points,   // B*N*3
    const float* __restrict__ radius,   // B*N
    const float* __restrict__ w2v,      // B*16
    const float* __restrict__ proj,     // B*16
    float* __restrict__ out,            // 3 * B*H*W*KPP floats
    int B, int N, int H, int W)
{
    extern __shared__ char smem[];
    float4* cmp  = (float4*)smem;                                     // N+2*BW
    int*    cidx = (int*)(smem + (size_t)(N + 2 * BW) * sizeof(float4));
    __shared__ int wsum[4];

    const int tid      = threadIdx.x;
    const int tilesX   = W / TS;
    const int tilesPer = tilesX * (H / TS);
    const int tile     = blockIdx.x % tilesPer;
    const int b        = blockIdx.x / tilesPer;
    const int tx0      = (tile % tilesX) * TS;
    const int ty0      = (tile / tilesX) * TS;
    const int j        = tx0 + (tid & (TS - 1));
    const int i        = ty0 + (tid >> 4);
    const int lane     = tid & 63;
    const int wid      = tid >> 6;

    const float* M1 = w2v  + (size_t)b * 16;
    const float* M2 = proj + (size_t)b * 16;

    const double halfd = 1.0 - 1.0 / (double)W;
    const double stepd = 2.0 * halfd / (double)(W - 1);
    const float px = (float)(halfd - (double)j * stepd);
    const float py = (float)(halfd - (double)i * stepd);
    const float cx = (float)(halfd - ((double)tx0 + (TS - 1) * 0.5) * stepd);
    const float cy = (float)(halfd - ((double)ty0 + (TS - 1) * 0.5) * stepd);
    const float hext = (float)(((TS - 1) * 0.5 + 1.0) * stepd);  // +1px inflation

    // ---- Phase 1: transform 4 points/thread, cull to tile box (R5-exact) ----
    const int t0 = tid * 4;
    float4 P[4];
    int keep[4];
    int c = 0;

    const float4* pv = (const float4*)(points + ((size_t)b * N + t0) * 3);
    float4 q0 = pv[0], q1 = pv[1], q2 = pv[2];
    float4 rr = *(const float4*)(radius + (size_t)b * N + t0);
    float xs[4] = {q0.x, q0.w, q1.z, q2.y};
    float ys[4] = {q0.y, q1.x, q1.w, q2.z};
    float zs[4] = {q0.z, q1.y, q2.x, q2.w};
    float rv[4] = {rr.x, rr.y, rr.z, rr.w};

#pragma unroll
    for (int s = 0; s < 4; ++s) {
        float x = xs[s], y = ys[s], z = zs[s];
        float vx = ((x * M1[0] + y * M1[4]) + z * M1[8])  + M1[12];
        float vy = ((x * M1[1] + y * M1[5]) + z * M1[9])  + M1[13];
        float vz = ((x * M1[2] + y * M1[6]) + z * M1[10]) + M1[14];
        float vw = ((x * M1[3] + y * M1[7]) + z * M1[11]) + M1[15];
        float w1 = (fabsf(vw) < 1e-8f) ? 1e-8f : vw;
        vx /= w1; vy /= w1; vz /= w1;
        float sx = ((vx * M2[0] + vy * M2[4]) + vz * M2[8])  + M2[12];
        float sy = ((vx * M2[1] + vy * M2[5]) + vz * M2[9])  + M2[13];
        float sw = ((vx * M2[3] + vy * M2[7]) + vz * M2[11]) + M2[15];
        float w2 = (fabsf(sw) < 1e-8f) ? 1e-8f : sw;
        sx /= w2; sy /= w2;
        float r = rv[s];
        float r2eff = (vz > 0.0f) ? r * r : -1.0f;
        float dxm = fmaxf(0.0f, fabsf(sx - cx) - hext);
        float dym = fmaxf(0.0f, fabsf(sy - cy) - hext);
        float dmin2 = dxm * dxm + dym * dym;
        keep[s] = (dmin2 <= r2eff + 1e-6f) ? 1 : 0;
        P[s] = make_float4(sx, sy, vz, r2eff);
        c += keep[s];
    }

    // ---- order-preserving compaction ----
    int pre = c;
#pragma unroll
    for (int d = 1; d < 64; d <<= 1) {
        int v = __shfl_up(pre, d);
        if (lane >= d) pre += v;
    }
    if (lane == 63) wsum[wid] = pre;
    __syncthreads();
    int wbase = 0, M = 0;
#pragma unroll
    for (int w = 0; w < 4; ++w) {
        int s = wsum[w];
        if (w < wid) wbase += s;
        M += s;
    }
    int pos = wbase + (pre - c);
#pragma unroll
    for (int s = 0; s < 4; ++s) {
        if (keep[s]) { cmp[pos] = P[s]; cidx[pos] = t0 + s; ++pos; }
    }
    const int Mpad = (M + 2 * BW - 1) & ~(2 * BW - 1);
    if (tid < Mpad - M) {
        cmp[M + tid]  = make_float4(0.0f, 0.0f, 0.0f, -1.0f);  // r2=-1: never inside
        cidx[M + tid] = -1;
    }
    __syncthreads();

    // ---- Phase 2: double-buffered 8-wide scan, packed-u64 top-K ----
    unsigned long long kb[KPP];
#pragma unroll
    for (int k = 0; k < KPP; ++k) kb[k] = ~0ULL;

    auto process = [&](const float4* pp, int base) {
#pragma unroll
        for (int u = 0; u < BW; ++u) {
            float dx = pp[u].x - px;
            float dy = pp[u].y - py;
            float dist2 = __fadd_rn(__fmul_rn(dx, dx), __fmul_rn(dy, dy));
            unsigned long long key =
                ((unsigned long long)__float_as_uint(pp[u].z) << 32) |
                (unsigned)(base + u);
            if ((dist2 <= pp[u].w) && (key < kb[KPP - 1])) {
                unsigned long long kc = key;
#pragma unroll
                for (int k2 = 0; k2 < KPP; ++k2) {
                    unsigned long long t = kb[k2];
                    bool lt = (kc < t);
                    kb[k2] = lt ? kc : t;   // min
                    kc     = lt ? t  : kc;  // max carries on
                }
            }
        }
    };

    float4 pa[BW];
    float4 pb[BW];

#pragma unroll
    for (int u = 0; u < BW; ++u) pa[u] = cmp[u];

    for (int n = 0; n < Mpad; n += 2 * BW) {
#pragma unroll
        for (int u = 0; u < BW; ++u) pb[u] = cmp[n + BW + u];
        process(pa, n);
        if (n + 2 * BW < Mpad) {
#pragma unroll
            for (int u = 0; u < BW; ++u) pa[u] = cmp[n + 2 * BW + u];
        }
        process(pb, n + BW);
    }

    // ---- Phase 3: unpack keys, recompute dist2 bit-identically, nt-store ----
    const size_t pix   = ((size_t)b * H + i) * W + j;
    const size_t plane = (size_t)B * H * W * KPP;
    float vidx[KPP], vzbf[KPP], vdst[KPP];
#pragma unroll
    for (int k = 0; k < KPP; ++k) {
        unsigned long long key = kb[k];
        bool valid = (key != ~0ULL);
        int p2 = valid ? (int)(key & 0xFFFFFFFFu) : 0;
        float4 p = cmp[p2];
        int idx  = cidx[p2];
        float dx = p.x - px;
        float dy = p.y - py;
        float dist2 = __fadd_rn(__fmul_rn(dx, dx), __fmul_rn(dy, dy));
        float z = __uint_as_float((unsigned)(key >> 32));
        vidx[k] = valid ? (float)idx : -1.0f;
        vzbf[k] = valid ? z          : -1.0f;
        vdst[k] = valid ? dist2      : -1.0f;
    }
    float* oidx = out + pix * KPP;
    float* ozbf = out + plane + pix * KPP;
    float* odst = out + 2 * plane + pix * KPP;
    nt_store4(oidx,     vidx[0], vidx[1], vidx[2], vidx[3]);
    nt_store4(oidx + 4, vidx[4], vidx[5], vidx[6], vidx[7]);
    nt_store4(ozbf,     vzbf[0], vzbf[1], vzbf[2], vzbf[3]);
    nt_store4(ozbf + 4, vzbf[4], vzbf[5], vzbf[6], vzbf[7]);
    nt_store4(odst,     vdst[0], vdst[1], vdst[2], vdst[3]);
    nt_store4(odst + 4, vdst[4], vdst[5], vdst[6], vdst[7]);
}

extern "C" void kernel_launch(void* const* d_in, const int* in_sizes, int n_in,
                              void* d_out, int out_size, void* d_ws, size_t ws_size,
                              hipStream_t stream) {
    const float* points = (const float*)d_in[0];
    const float* radius = (const float*)d_in[1];
    const float* w2v    = (const float*)d_in[2];
    const float* proj   = (const float*)d_in[3];
    int B = in_sizes[2] / 16;
    if (B < 1) B = 1;
    int N = in_sizes[1] / B;
    int HW = out_size / (3 * B * KPP);
    int H = 1;
    while ((H + 1) * (H + 1) <= HW) ++H;     // integer sqrt
    int W = H;

    int tiles = (W / TS) * (H / TS);
    size_t shmem = (size_t)(N + 2 * BW) * (sizeof(float4) + sizeof(int));
    sphere_raster_kernel<<<B * tiles, 256, shmem, stream>>>(
        points, radius, w2v, proj, (float*)d_out, B, N, H, W);
}